// Round 11
// baseline (20122.800 us; speedup 1.0000x reference)
//
#include <hip/hip_runtime.h>

// ---------------------------------------------------------------------------
// RevRNN persistent kernel, round 14: XCD-local exchange, correctness-first.
// r7 (14.76ms) protocol/compute verbatim; only the exchange DOMAIN changes:
// all 32 workers claimed onto ONE XCD, exchange via that XCD's L2 (~250cy RT)
// instead of agent-scope MALL (~2-2.5k cy RT, measured via r3/r7 deltas).
// - Truth channel: L2-point atomics. CDNA L1 has no atomic path -> atomics
//   execute at L2 when not sc1-scoped. Producer: global_atomic_swap(_x2)
//   fire-and-forget. Consumer fallback: global_atomic_or_x2 with 0 (sc0 =
//   return-old) = L2-coherent load, immune to stale L1 (r4's failure mode).
// - Fast path: per-WG per-parity flag (swapped AFTER the end-barrier vmcnt
//   drain => flag strictly follows payload). Wave0 lanes 0-11 poll the 12
//   producer flags (32b L2 atomics, ~400 RMW/iter machine-wide); LDS go_tag
//   relays. Then bulk plain `sc0 nt` loads of the 12 tagged words + tag
//   VERIFY; stale words -> atomic fallback. Wrong sc0 semantics => slow but
//   CORRECT (self-diagnosing).
// - Claim: 1024 WGs; tid0 reads HW_REG_XCC_ID (m09-verified), CAS-elects an
//   XCD, tickets 0..31 on it become workers; rest exit. Under-fill => sticky
//   guard => loud wrong answer, never a hang.
// ---------------------------------------------------------------------------

#define T_TOT 2056
#define S_SEQ 2048

typedef _Float16 f16x8 __attribute__((ext_vector_type(8)));
typedef float f32x4 __attribute__((ext_vector_type(4)));

// exchange arrays: static device globals
__device__ unsigned long long g_st0[8192];  // [64 rows][128 colpair cells]
__device__ unsigned long long g_st1[8192];
__device__ unsigned long long g_pa0[1024];  // [256 ocol][4 b-groups]
__device__ unsigned long long g_pa1[1024];
__device__ unsigned g_fl[2][32];            // [tag parity][producer wg]
__device__ unsigned g_ctrl[2];              // [chosen xcd+1, ticket]

__global__ void init_ws() {
  const int i = (int)blockIdx.x * 256 + (int)threadIdx.x;  // 8192 threads
  g_st0[i] = 0ull;
  g_st1[i] = 0ull;
  if (i < 1024) { g_pa0[i] = 0ull; g_pa1[i] = 0ull; }
  if (i < 64) g_fl[i >> 5][i & 31] = 0u;
  if (i < 2) g_ctrl[i] = 0u;
}

// L2-point atomic ops (no sc1 => executed at this XCD's L2; L1 cannot serve)
#define ASWAP64(P, V)                                                          \
  asm volatile("global_atomic_swap_x2 %0, %1, off"                             \
               :: "v"((void*)(P)), "v"((unsigned long long)(V)) : "memory")
#define ASWAP32(P, V)                                                          \
  asm volatile("global_atomic_swap %0, %1, off"                                \
               :: "v"((void*)(P)), "v"((unsigned)(V)) : "memory")

// atomic truth-channel reload of word W from P until tag >= tg_ (sticky).
#define CHK(W, P)                                                              \
  {                                                                            \
    int itc_ = 0;                                                              \
    while ((unsigned)((W) >> 32) < tg_) {                                      \
      if (!alive || ++itc_ > (1 << 16)) { alive = 0; break; }                  \
      unsigned long long zz_ = 0ull, rr_;                                      \
      asm volatile("global_atomic_or_x2 %0, %1, %2, off sc0\n\t"               \
                   "s_waitcnt vmcnt(0)"                                        \
                   : "=&v"(rr_) : "v"((void*)(P)), "v"(zz_) : "memory");       \
      (W) = rr_;                                                               \
    }                                                                          \
  }

// One phase: flag-hint detect (wave0 + LDS relay) -> bulk sc0-nt load ->
// tag verify (+atomic fallback) -> LDS -> barrier -> centered MFMA -> gate
// -> swap publish -> end barrier (drains swaps) -> tid0 flag swap.
#define PHASE(WS, SIN, PIN, TAGIN, SOUT, POUT, TAGOUT, RAW)                    \
  {                                                                            \
    const unsigned tg_ = (unsigned)(TAGIN);                                    \
    if (wv == 0) {                                                             \
      if (ln < 12) {                                                           \
        const int prod_ = (ln < 4) ? (4 * c + ln) : (4 * (ln - 4) + b);        \
        unsigned* fp_ = &g_fl[tg_ & 1][prod_];                                 \
        int it_ = 0;                                                           \
        for (;;) {                                                             \
          unsigned fv_, z32_ = 0u;                                             \
          asm volatile("global_atomic_or %0, %1, %2, off sc0\n\t"              \
                       "s_waitcnt vmcnt(0)"                                    \
                       : "=&v"(fv_) : "v"((void*)fp_), "v"(z32_) : "memory");  \
          if (fv_ >= tg_) break;                                               \
          if (!alive || ++it_ > (1 << 17)) { alive = 0; break; }               \
        }                                                                      \
      }                                                                        \
      if (ln == 0) *gop = tg_;                                                 \
    } else {                                                                   \
      int it_ = 0;                                                             \
      while (*gop < tg_) {                                                     \
        if (!alive || ++it_ > (1 << 18)) { alive = 0; break; }                 \
      }                                                                        \
    }                                                                          \
    const unsigned long long* pp_ = (PIN) + 4 * tid;                           \
    const unsigned long long* sp_ =                                            \
        (SIN) + (size_t)(16 * b + n) * 128 + (2 * wv) * 16 + kq * 4;           \
    unsigned long long q0_, q1_, q2_, q3_;                                     \
    unsigned long long s0_, s1_, s2_, s3_, s4_, s5_, s6_, s7_;                 \
    asm volatile("global_load_dwordx2 %0, %12, off sc0 nt\n\t"                 \
                 "global_load_dwordx2 %1, %12, off offset:8 sc0 nt\n\t"        \
                 "global_load_dwordx2 %2, %12, off offset:16 sc0 nt\n\t"       \
                 "global_load_dwordx2 %3, %12, off offset:24 sc0 nt\n\t"       \
                 "global_load_dwordx2 %4, %13, off sc0 nt\n\t"                 \
                 "global_load_dwordx2 %5, %13, off offset:8 sc0 nt\n\t"        \
                 "global_load_dwordx2 %6, %13, off offset:16 sc0 nt\n\t"       \
                 "global_load_dwordx2 %7, %13, off offset:24 sc0 nt\n\t"       \
                 "global_load_dwordx2 %8, %13, off offset:128 sc0 nt\n\t"      \
                 "global_load_dwordx2 %9, %13, off offset:136 sc0 nt\n\t"      \
                 "global_load_dwordx2 %10, %13, off offset:144 sc0 nt\n\t"     \
                 "global_load_dwordx2 %11, %13, off offset:152 sc0 nt\n\t"     \
                 "s_waitcnt vmcnt(0)"                                          \
                 : "=&v"(q0_), "=&v"(q1_), "=&v"(q2_), "=&v"(q3_),             \
                   "=&v"(s0_), "=&v"(s1_), "=&v"(s2_), "=&v"(s3_),             \
                   "=&v"(s4_), "=&v"(s5_), "=&v"(s6_), "=&v"(s7_)              \
                 : "v"(pp_), "v"(sp_) : "memory");                             \
    CHK(q0_, pp_ + 0) CHK(q1_, pp_ + 1) CHK(q2_, pp_ + 2) CHK(q3_, pp_ + 3)    \
    CHK(s0_, sp_ + 0) CHK(s1_, sp_ + 1) CHK(s2_, sp_ + 2) CHK(s3_, sp_ + 3)    \
    CHK(s4_, sp_ + 16) CHK(s5_, sp_ + 17) CHK(s6_, sp_ + 18)                   \
    CHK(s7_, sp_ + 19)                                                         \
    const float mean_ = (__uint_as_float((unsigned)q0_) +                      \
                         __uint_as_float((unsigned)q1_) +                      \
                         __uint_as_float((unsigned)q2_) +                      \
                         __uint_as_float((unsigned)q3_)) * 0.015625f;          \
    mean_h[tid] = (_Float16)mean_;                                             \
    {                                                                          \
      unsigned long long* lp_ =                                                \
          (unsigned long long*)&lds_s[n][(2 * wv) * 16 + kq * 4];              \
      lp_[0] = ((unsigned long long)(unsigned)s1_ << 32) | (unsigned)s0_;      \
      lp_[1] = ((unsigned long long)(unsigned)s3_ << 32) | (unsigned)s2_;      \
      lp_[8] = ((unsigned long long)(unsigned)s5_ << 32) | (unsigned)s4_;      \
      lp_[9] = ((unsigned long long)(unsigned)s7_ << 32) | (unsigned)s6_;      \
    }                                                                          \
    __syncthreads();                                                           \
    _Pragma("unroll")                                                          \
    for (int kk = 0; kk < 8; ++kk) {                                           \
      const f16x8 sv_ = *(const f16x8*)&lds_s[n][kk * 16 + kq * 4];            \
      const f16x8 mv_ = *(const f16x8*)&mean_h[kk * 32 + kq * 8];              \
      if (kk & 1)                                                              \
        acc1 = __builtin_amdgcn_mfma_f32_16x16x32_f16(sv_ - mv_, (WS)[kk],     \
                                                      acc1, 0, 0, 0);          \
      else                                                                     \
        acc0 = __builtin_amdgcn_mfma_f32_16x16x32_f16(sv_ - mv_, (WS)[kk],     \
                                                      acc0, 0, 0, 0);          \
    }                                                                          \
    float nv_[4], ssum_ = 0.f;                                                 \
    _Pragma("unroll")                                                          \
    for (int r = 0; r < 4; ++r) {                                              \
      const float z = acc0[r] + acc1[r];                                       \
      const float p = __shfl_xor(z, 8);                                        \
      const float z0 = (n < 8) ? z : p;                                        \
      const float z1 = (n < 8) ? p : z;                                        \
      /* branch-free tanh: clamp +-10, (e-1)/(e+1); err << f16 quantization */ \
      const float z1c = fminf(fmaxf(z1, -10.f), 10.f);                         \
      const float e2 = __expf(2.f * z1c);                                      \
      const float th = (e2 - 1.f) * __builtin_amdgcn_rcpf(e2 + 1.f);           \
      const float cv = fminf(fmaxf(z0, 0.f), 6.f) * th;                        \
      const float o = ((RAW)[r] + cv) * 0.5f;                                  \
      (RAW)[r] = o; nv_[r] = o; ssum_ += o;                                    \
    }                                                                          \
    ssum_ += __shfl_xor(ssum_, 16);                                            \
    ssum_ += __shfl_xor(ssum_, 32);                                            \
    _Pragma("unroll")                                                          \
    for (int r = 0; r < 4; ++r) {                                              \
      union { _Float16 h; unsigned short u; } hb_;                             \
      hb_.h = (_Float16)nv_[r];                                                \
      const unsigned pr_ = (unsigned)__shfl_xor((int)hb_.u, 1) & 0xFFFFu;      \
      if ((n & 1) == 0 && n < 8) {                                             \
        const unsigned dw_ = (unsigned)hb_.u | (pr_ << 16);                    \
        ASWAP64((SOUT) + (size_t)(16 * b + kq * 4 + r) * 128 + (ocol >> 1),    \
                ((unsigned long long)(unsigned)(TAGOUT) << 32) |               \
                    (unsigned long long)dw_);                                  \
      }                                                                        \
    }                                                                          \
    if (kq == 0 && n < 8)                                                      \
      ASWAP64((POUT) + (size_t)ocol * 4 + b,                                   \
              ((unsigned long long)(unsigned)(TAGOUT) << 32) |                 \
                  (unsigned long long)__float_as_uint(ssum_));                 \
    __syncthreads(); /* drains swaps (L2, cheap) + lds_s/mean_h epoch */       \
    if (tid == 0) ASWAP32(&g_fl[(unsigned)(TAGOUT) & 1][wg],                   \
                          (unsigned)(TAGOUT));                                 \
  }

__launch_bounds__(256, 1)
__global__ void rnn_kernel(const float* __restrict__ xg,
                           const float* __restrict__ hs,
                           const float* __restrict__ W0,
                           const float* __restrict__ W1,
                           float* __restrict__ out) {
  const int tid = (int)threadIdx.x;
  __shared__ int role_sh;
  __shared__ volatile unsigned go_tag;

  // ---- single-XCD worker claim: tickets 0..31 on the first-claimed XCD ---
  if (tid == 0) {
    unsigned xcd;
    asm volatile("s_getreg_b32 %0, hwreg(HW_REG_XCC_ID)" : "=s"(xcd));
    const unsigned me = xcd + 1u;
    const unsigned prev = atomicCAS(&g_ctrl[0], 0u, me);  // device scope
    const unsigned tgt = (prev == 0u) ? me : prev;
    int role = -1;
    if (me == tgt) {
      const unsigned tk = atomicAdd(&g_ctrl[1], 1u);
      if (tk < 32u) role = (int)tk;
    }
    role_sh = role;
    go_tag = 0u;
  }
  __syncthreads();
  const int wg = role_sh;
  if (wg < 0) return;                       // non-workers exit

  const int b = wg & 3;                     // batch group: rows 16b..16b+15
  const int c = wg >> 2;                    // col group: o-cols 32c..32c+31
  const int wv = tid >> 6;                  // wave 0..3
  const int ln = tid & 63;
  const int n = ln & 15;                    // packed col in tile / A-row
  const int kq = ln >> 4;                   // quad 0..3
  const int ocol = c * 32 + wv * 8 + (n & 7);      // owned output column
  const int wrow = (n < 8) ? ocol : (256 + ocol);  // packed W row (z0|z1)
  volatile unsigned* gop = &go_tag;

  __shared__ __align__(16) unsigned lds_s[16][132];   // state payload, padded
  __shared__ __align__(16) _Float16 mean_h[256];

  // ---- preload W fragments (state part + x part) into registers ----
  f16x8 w0s[8], w0x[8], w1s[8], w1x[8];
  float w0pa, w0pb, w1pa, w1pb;
  {
    const float* r0 = W0 + (size_t)wrow * 514;
    const float* r1 = W1 + (size_t)wrow * 514;
#pragma unroll
    for (int kk = 0; kk < 8; ++kk) {
      const int k0 = kk * 32 + kq * 8;
      f16x8 a, bx, a1, bx1;
#pragma unroll
      for (int j = 0; j < 8; ++j) {
        a[j]   = (_Float16)r0[k0 + j];
        bx[j]  = (_Float16)r0[256 + k0 + j];
        a1[j]  = (_Float16)r1[k0 + j];
        bx1[j] = (_Float16)r1[256 + k0 + j];
      }
      w0s[kk] = a; w0x[kk] = bx; w1s[kk] = a1; w1x[kk] = bx1;
    }
    w0pa = r0[512]; w0pb = r0[513];
    w1pa = r1[512]; w1pb = r1[513];
  }

  // ---- raw recurrence state (fp32, register-resident) ----
  float raw0[4], raw1[4];
#pragma unroll
  for (int r = 0; r < 4; ++r) { raw0[r] = hs[ocol]; raw1[r] = hs[256 + ocol]; }

  int alive = 1;

  // ---- init publish: tagged h0 pairs + partials (tag 1), swaps; then flag --
  {
    union { _Float16 h; unsigned short u; } e0, e1;
    e0.h = (_Float16)hs[ocol]; e1.h = (_Float16)hs[ocol + 1];
    const unsigned dw = (unsigned)e0.u | ((unsigned)e1.u << 16);
    if ((n & 1) == 0 && n < 8) {
#pragma unroll
      for (int r = 0; r < 4; ++r)
        ASWAP64(g_st0 + (size_t)(16 * b + kq * 4 + r) * 128 + (ocol >> 1),
                (1ull << 32) | (unsigned long long)dw);
    }
    if (kq == 0 && n < 8)
      ASWAP64(g_pa0 + (size_t)ocol * 4 + b,
              (1ull << 32) |
                  (unsigned long long)__float_as_uint(16.f * hs[ocol]));
  }
  __syncthreads();  // drains init swaps before the init flag
  if (tid == 0) ASWAP32(&g_fl[1][wg], 1u);

  // ---- x prefetch for t=0 ----
  f32x4 xf[16];
  f16x8 xa[8];
  const int arow = 16 * b + n;
  {
    const float* xp = xg + (size_t)arow * S_SEQ * 256 + kq * 8;
#pragma unroll
    for (int kk = 0; kk < 8; ++kk) {
      xf[2 * kk]     = *(const f32x4*)(xp + kk * 32);
      xf[2 * kk + 1] = *(const f32x4*)(xp + kk * 32 + 4);
    }
  }

  for (int t = 0; t < T_TOT; ++t) {
    const float pe0 = (float)(t + 1);
    const float pe1 = (pe0 - 1028.5f) * (1.0f / 1028.5f);
    const int have_x = (t < S_SEQ);

    // ---------------- phase A: o1 = (h1 + calc(h0c, s, W0)) * 0.5 ----------
    {
      f32x4 acc0, acc1;
      const float pt = pe0 * w0pa + pe1 * w0pb;
      acc0[0] = pt; acc0[1] = pt; acc0[2] = pt; acc0[3] = pt;
      acc1[0] = 0.f; acc1[1] = 0.f; acc1[2] = 0.f; acc1[3] = 0.f;
      // x part BEFORE the detect: overlaps the wait, off the critical path.
      if (have_x) {
#pragma unroll
        for (int kk = 0; kk < 8; ++kk) {
          f16x8 af;
#pragma unroll
          for (int j = 0; j < 4; ++j) {
            af[j]     = (_Float16)xf[2 * kk][j];
            af[4 + j] = (_Float16)xf[2 * kk + 1][j];
          }
          xa[kk] = af;
          if (kk & 1)
            acc1 = __builtin_amdgcn_mfma_f32_16x16x32_f16(af, w0x[kk], acc1,
                                                          0, 0, 0);
          else
            acc0 = __builtin_amdgcn_mfma_f32_16x16x32_f16(af, w0x[kk], acc0,
                                                          0, 0, 0);
        }
      }
      PHASE(w0s, g_st0, g_pa0, 2 * t + 1, g_st1, g_pa1, 2 * t + 2, raw1);
    }

    // ---------------- phase B: o0 = (h0 + calc(o1c, s, W1)) * 0.5 ----------
    {
      f32x4 acc0, acc1;
      const float pt = pe0 * w1pa + pe1 * w1pb;
      acc0[0] = pt; acc0[1] = pt; acc0[2] = pt; acc0[3] = pt;
      acc1[0] = 0.f; acc1[1] = 0.f; acc1[2] = 0.f; acc1[3] = 0.f;
      if (have_x) {
#pragma unroll
        for (int kk = 0; kk < 8; ++kk) {
          if (kk & 1)
            acc1 = __builtin_amdgcn_mfma_f32_16x16x32_f16(xa[kk], w1x[kk],
                                                          acc1, 0, 0, 0);
          else
            acc0 = __builtin_amdgcn_mfma_f32_16x16x32_f16(xa[kk], w1x[kk],
                                                          acc0, 0, 0, 0);
        }
      }
      // prefetch x(t+1): in flight across detect B + phase-A conversion.
      if (t + 1 < S_SEQ) {
        const float* xp = xg + ((size_t)arow * S_SEQ + (t + 1)) * 256 + kq * 8;
#pragma unroll
        for (int kk = 0; kk < 8; ++kk) {
          xf[2 * kk]     = *(const f32x4*)(xp + kk * 32);
          xf[2 * kk + 1] = *(const f32x4*)(xp + kk * 32 + 4);
        }
      }
      PHASE(w1s, g_st1, g_pa1, 2 * t + 2, g_st0, g_pa0, 2 * t + 3, raw0);
    }
  }

  // ---- final h = [o0 | o1] fp32 ----
  if (n < 8) {
#pragma unroll
    for (int r = 0; r < 4; ++r) {
      const int row = 16 * b + kq * 4 + r;
      out[(size_t)row * 512 + ocol] = raw0[r];
      out[(size_t)row * 512 + 256 + ocol] = raw1[r];
    }
  }
}

#undef PHASE
#undef CHK
#undef ASWAP32
#undef ASWAP64

extern "C" void kernel_launch(void* const* d_in, const int* in_sizes, int n_in,
                              void* d_out, int out_size, void* d_ws, size_t ws_size,
                              hipStream_t stream) {
  (void)in_sizes; (void)n_in; (void)out_size; (void)d_ws; (void)ws_size;
  const float* x  = (const float*)d_in[0];
  const float* hs = (const float*)d_in[1];
  const float* W0 = (const float*)d_in[2];
  const float* W1 = (const float*)d_in[3];
  float* out = (float*)d_out;

  // prologue zeroes exchange globals + claim ctrl (stream-ordered; replayed
  // per graph iteration so tags/claim reset each run). No workspace use.
  init_ws<<<dim3(32), dim3(256), 0, stream>>>();
  // oversubscribe so >=32 WGs land on the chosen XCD; non-workers exit fast
  rnn_kernel<<<dim3(1024), dim3(256), 0, stream>>>(x, hs, W0, W1, out);
}